// Round 9
// baseline (985.193 us; speedup 1.0000x reference)
//
#include <hip/hip_runtime.h>

// Bidirectional masked LSTM, only last timestep consumed.
//   B=256, T=2048, VOCAB=6, EMB=64, HID=64.  One block per batch element/CU.
// Algebraic reductions (validated rounds 0-6, absmax 0.0):
//   - bwd direction at t=T-1 == ONE lstm step from zero state (U_b unused).
//   - x@W+b has only 6 values per direction -> zx tables.
//   - tok==0 steps are no-ops -> token stream compacted once.
// Round-7/8 fix. R3..R6 evidence: the allocator NEVER keeps 64 U floats in
// VGPRs (VGPR=52 constant; FETCH 1.85GB = 64KB/step/block reload @ ~6%
// L2-miss, regardless of volatile/named-scalar/asm-pin hints). Stop hinting:
//   U lives in 64 AGPRs (explicit v_accvgpr_write with "a" constraint; the
//   accumulator file is idle here). Loop does volatile v_accvgpr_read + fmaf:
//   zero memory ops / vmcnt stalls in the recurrence.
// Core predicted delta: FETCH_SIZE 1855MB -> ~50MB, dur 706 -> ~420-500us.
// (R8 = identical resubmit; R8 bench lost to GPU acquisition timeout.)

#define TT 2048
#define L2E 1.4426950408889634f

__device__ __forceinline__ float fexp2(float x) { return __builtin_amdgcn_exp2f(x); }
__device__ __forceinline__ float frcp(float x)  { return __builtin_amdgcn_rcpf(x); }
__device__ __forceinline__ float fsigm(float x) { return frcp(1.f + fexp2(-L2E * x)); }
__device__ __forceinline__ float ftanh(float x) { return fmaf(2.f, frcp(1.f + fexp2(-2.f * L2E * x)), -1.f); }
__device__ __forceinline__ float readlane_f(float v, int l) {
  return __builtin_bit_cast(float, __builtin_amdgcn_readlane(__builtin_bit_cast(int, v), l));
}

// apply X to 0..63
#define UFOR_ALL(X) \
  X(0)  X(1)  X(2)  X(3)  X(4)  X(5)  X(6)  X(7)  \
  X(8)  X(9)  X(10) X(11) X(12) X(13) X(14) X(15) \
  X(16) X(17) X(18) X(19) X(20) X(21) X(22) X(23) \
  X(24) X(25) X(26) X(27) X(28) X(29) X(30) X(31) \
  X(32) X(33) X(34) X(35) X(36) X(37) X(38) X(39) \
  X(40) X(41) X(42) X(43) X(44) X(45) X(46) X(47) \
  X(48) X(49) X(50) X(51) X(52) X(53) X(54) X(55) \
  X(56) X(57) X(58) X(59) X(60) X(61) X(62) X(63)

// U[k] -> AGPR (one-time). "a" output forces AGPR allocation.
#define DECLUA(k)                                                        \
  float Ua##k;                                                           \
  {                                                                      \
    float tmp = U_f[(k) * 256 + cb];                                     \
    asm("v_accvgpr_write_b32 %0, %1" : "=a"(Ua##k) : "v"(tmp));          \
  }

// one k-term: AGPR -> VGPR (volatile: stays inside the loop, no 64-wide
// VGPR hoist) then fma with the SGPR broadcast of h[k].
#define FMAK(k, acc)                                                     \
  {                                                                      \
    float u_;                                                            \
    asm volatile("v_accvgpr_read_b32 %0, %1" : "=v"(u_) : "a"(Ua##k));   \
    acc = fmaf(readlane_f(h_reg, k), u_, acc);                           \
  }

#define FMA4(k0, k1, k2, k3) \
  FMAK(k0, a0) FMAK(k1, a1) FMAK(k2, a2) FMAK(k3, a3)

__global__ __launch_bounds__(256, 1) void lstm_fused(
    const int* __restrict__ tokens,
    const float* __restrict__ emb,
    const float* __restrict__ W_f, const float* __restrict__ U_f, const float* __restrict__ b_f,
    const float* __restrict__ W_b, const float* __restrict__ b_b,
    const float* __restrict__ W_d, const float* __restrict__ b_d,
    float* __restrict__ out)
{
  const int b    = blockIdx.x;
  const int tid  = threadIdx.x;
  const int lane = tid & 63;      // unit u = lane
  const int g    = tid >> 6;      // wave == gate: 0:i 1:f 2:g(tanh) 3:o

  __shared__ int   tok_s [TT + 8];
  __shared__ int   ctok_s[TT + 8];      // compacted active tokens
  __shared__ float emb_s[6 * 64];
  __shared__ float zx_s [6 * 272];      // fwd table, [v][g*68 + u] (padded)
  __shared__ float zxb_s[6 * 256];      // bwd table (epilogue only)
  __shared__ float act_s[2][4 * 68];    // [buf][g*68 + u]
  __shared__ int   wsum[4];

  // ---- stage tokens (int4) + emb ----
  {
    const int4* tsrc = (const int4*)(tokens + b * TT);
    int4* tdst = (int4*)tok_s;
    for (int i = tid; i < TT / 4; i += 256) tdst[i] = tsrc[i];
    if (tid < 8) { tok_s[TT + tid] = 0; ctok_s[TT + tid] = 0; }
    for (int i = tid; i < 384; i += 256) emb_s[i] = emb[i];
  }
  __syncthreads();

  // ---- compact active tokens: stable parallel scan (8 tokens/thread) ----
  int mytok[8];
  int cnt = 0;
#pragma unroll
  for (int j = 0; j < 8; ++j) {
    mytok[j] = tok_s[tid * 8 + j];
    cnt += (mytok[j] != 0);
  }
  int inc = cnt;                        // wave-inclusive scan
#pragma unroll
  for (int off = 1; off < 64; off <<= 1) {
    int v = __shfl_up(inc, off, 64);
    if (lane >= off) inc += v;
  }
  if (lane == 63) wsum[g] = inc;
  __syncthreads();
  int base = 0;
#pragma unroll
  for (int w = 0; w < 4; ++w) base += (w < g) ? wsum[w] : 0;
  int pos = base + inc - cnt;           // exclusive global offset
#pragma unroll
  for (int j = 0; j < 8; ++j)
    if (mytok[j] != 0) ctok_s[pos++] = mytok[j];
  const int nact = __builtin_amdgcn_readfirstlane(wsum[0] + wsum[1] + wsum[2] + wsum[3]);

  // ---- zx tables (thread owns column (g,lane), both dirs) ----
  {
    float af[6], ab[6];
#pragma unroll
    for (int v = 0; v < 6; ++v) { af[v] = b_f[tid]; ab[v] = b_b[tid]; }
    for (int e = 0; e < 64; ++e) {
      const float wf = W_f[e * 256 + tid];
      const float wb = W_b[e * 256 + tid];
#pragma unroll
      for (int v = 0; v < 6; ++v) {
        af[v] = fmaf(emb_s[v * 64 + e], wf, af[v]);
        ab[v] = fmaf(emb_s[v * 64 + e], wb, ab[v]);
      }
    }
#pragma unroll
    for (int v = 0; v < 6; ++v) {
      zx_s [v * 272 + g * 68 + lane] = af[v];
      zxb_s[v * 256 + tid] = ab[v];
    }
  }

  // ---- U column for (gate g, unit lane): 64 AGPRs ----
  const int cb = (g << 6) + lane;
  UFOR_ALL(DECLUA)

  __syncthreads();

  // wave-uniform activation constants: y = ya*rcp(1+exp2(z*m1)) + yb
  const float m1 = (g == 2) ? (-2.f * L2E) : (-L2E);
  const float ya = (g == 2) ? 2.f : 1.f;
  const float yb = (g == 2) ? -1.f : 0.f;
  const int   goff = g * 68 + lane;

  // h,c replicated per-lane in EVERY wave: lane l holds h[l], c[l]
  float h_reg = 0.f, c_reg = 0.f;
  int   buf = 0;
  int   tokc = ctok_s[0];

  for (int s = 0; s < nact; ++s) {
    const int tokn = ctok_s[s + 1];              // prefetch (pad-safe)
    const float zxv = zx_s[tokc * 272 + goff];   // issues under FMA block
    float a0 = 0.f, a1 = 0.f, a2 = 0.f, a3 = 0.f;
    FMA4(0, 1, 2, 3)     FMA4(4, 5, 6, 7)     FMA4(8, 9, 10, 11)   FMA4(12, 13, 14, 15)
    FMA4(16, 17, 18, 19) FMA4(20, 21, 22, 23) FMA4(24, 25, 26, 27) FMA4(28, 29, 30, 31)
    FMA4(32, 33, 34, 35) FMA4(36, 37, 38, 39) FMA4(40, 41, 42, 43) FMA4(44, 45, 46, 47)
    FMA4(48, 49, 50, 51) FMA4(52, 53, 54, 55) FMA4(56, 57, 58, 59) FMA4(60, 61, 62, 63)
    const float z = zxv + ((a0 + a1) + (a2 + a3));
    const float y = fmaf(ya, frcp(1.f + fexp2(z * m1)), yb);
    act_s[buf][goff] = y;
    __syncthreads();
    const float ai  = act_s[buf][lane];
    const float af2 = act_s[buf][68 + lane];
    const float ag  = act_s[buf][136 + lane];
    const float ao  = act_s[buf][204 + lane];
    c_reg = fmaf(af2, c_reg, ai * ag);           // replicated update, all waves
    h_reg = ao * ftanh(c_reg);
    buf ^= 1;                                    // WAR-safe: 2 barriers apart
    tokc = tokn;
  }

  // ---- epilogue: bwd single step from zero state + dense + reduce ----
  if (tid < 64) {                                // wave 0 holds h[lane] = h_reg
    const float hf   = h_reg;
    const int   tokL = tok_s[TT - 1];
    float hbv = 0.f;
    if (tokL != 0) {
      const float zi = zxb_s[tokL * 256 + tid];
      const float zg = zxb_s[tokL * 256 + 128 + tid];
      const float zo = zxb_s[tokL * 256 + 192 + tid];
      const float cn = fsigm(zi) * ftanh(zg);    // c0=0 -> forget term vanishes
      hbv = fsigm(zo) * ftanh(cn);
    }
    float pr = fmaf(hf, W_d[tid], hbv * W_d[64 + tid]);
#pragma unroll
    for (int off = 32; off > 0; off >>= 1) pr += __shfl_xor(pr, off, 64);
    if (tid == 0) out[b] = pr + b_d[0];
  }
}

extern "C" void kernel_launch(void* const* d_in, const int* in_sizes, int n_in,
                              void* d_out, int out_size, void* d_ws, size_t ws_size,
                              hipStream_t stream) {
  const int*   tokens = (const int*)d_in[0];
  const float* emb    = (const float*)d_in[1];
  const float* W_f    = (const float*)d_in[2];
  const float* U_f    = (const float*)d_in[3];
  const float* b_f    = (const float*)d_in[4];
  const float* W_b    = (const float*)d_in[5];
  const float* U_b    = (const float*)d_in[6];
  (void)U_b;  // bwd is a single step from zero state: h@U_b == 0
  const float* b_b    = (const float*)d_in[7];
  const float* W_d    = (const float*)d_in[8];
  const float* b_d    = (const float*)d_in[9];
  float* out = (float*)d_out;
  (void)d_ws; (void)ws_size;

  lstm_fused<<<256, 256, 0, stream>>>(tokens, emb, W_f, U_f, b_f, W_b, b_b,
                                      W_d, b_d, out);
}

// Round 10
// 880.702 us; speedup vs baseline: 1.1186x; 1.1186x over previous
//
#include <hip/hip_runtime.h>

// Bidirectional masked LSTM, only last timestep consumed.
//   B=256, T=2048, VOCAB=6, EMB=64, HID=64.  One block per batch element/CU.
// Algebraic reductions (validated rounds 0-9, absmax 0.0):
//   - bwd direction at t=T-1 == ONE lstm step from zero state (U_b unused).
//   - x@W+b has only 6 values per direction -> zx tables.
//   - tok==0 steps are no-ops -> token stream compacted once.
// Round-10. Evidence so far:
//   - R3/R6 (VGPR hints): allocator spills U to scratch (L2-resident; FETCH
//     1855MB is an artifact, NOT kernel HBM traffic - R9 proved it).
//   - R9 (AGPR + volatile reads): storage works, but volatile asm fences
//     serialized the read->fma pairs -> 967us (worse than R6's 706).
// This round: AGPR storage + NON-VOLATILE schedulable reads. Each
// v_accvgpr_read carries a data dependency on h_reg (loop-carried) so it
// cannot be hoisted out of the loop, but CAN be freely interleaved with
// readlanes/FMAs inside the iteration. Zero memory ops in the recurrence.
// Core predicted delta: dur 967 -> ~500-620us, VALUBusy -> 62-75%.

#define TT 2048
#define L2E 1.4426950408889634f

__device__ __forceinline__ float fexp2(float x) { return __builtin_amdgcn_exp2f(x); }
__device__ __forceinline__ float frcp(float x)  { return __builtin_amdgcn_rcpf(x); }
__device__ __forceinline__ float fsigm(float x) { return frcp(1.f + fexp2(-L2E * x)); }
__device__ __forceinline__ float ftanh(float x) { return fmaf(2.f, frcp(1.f + fexp2(-2.f * L2E * x)), -1.f); }
__device__ __forceinline__ float readlane_f(float v, int l) {
  return __builtin_bit_cast(float, __builtin_amdgcn_readlane(__builtin_bit_cast(int, v), l));
}

// apply X to 0..63
#define UFOR_ALL(X) \
  X(0)  X(1)  X(2)  X(3)  X(4)  X(5)  X(6)  X(7)  \
  X(8)  X(9)  X(10) X(11) X(12) X(13) X(14) X(15) \
  X(16) X(17) X(18) X(19) X(20) X(21) X(22) X(23) \
  X(24) X(25) X(26) X(27) X(28) X(29) X(30) X(31) \
  X(32) X(33) X(34) X(35) X(36) X(37) X(38) X(39) \
  X(40) X(41) X(42) X(43) X(44) X(45) X(46) X(47) \
  X(48) X(49) X(50) X(51) X(52) X(53) X(54) X(55) \
  X(56) X(57) X(58) X(59) X(60) X(61) X(62) X(63)

// U[k] -> AGPR (one-time). "a" output forces AGPR allocation.
#define DECLUA(k)                                                        \
  float Ua##k;                                                           \
  {                                                                      \
    float tmp = U_f[(k) * 256 + cb];                                     \
    asm("v_accvgpr_write_b32 %0, %1" : "=a"(Ua##k) : "v"(tmp));          \
  }

// one k-term: AGPR -> VGPR read. NON-volatile (schedulable, CSE-proof since
// each Ua differs) with a dummy dependency on h_reg (loop-carried) so the
// read can't be hoisted out of the loop into 64 live VGPRs.
#define FMAK(k, acc)                                                     \
  {                                                                      \
    float u_;                                                            \
    asm("v_accvgpr_read_b32 %0, %1"                                      \
        : "=v"(u_) : "a"(Ua##k), "v"(h_reg));                            \
    acc = fmaf(readlane_f(h_reg, k), u_, acc);                           \
  }

#define FMA4(k0, k1, k2, k3) \
  FMAK(k0, a0) FMAK(k1, a1) FMAK(k2, a2) FMAK(k3, a3)

__global__ __launch_bounds__(256, 1) void lstm_fused(
    const int* __restrict__ tokens,
    const float* __restrict__ emb,
    const float* __restrict__ W_f, const float* __restrict__ U_f, const float* __restrict__ b_f,
    const float* __restrict__ W_b, const float* __restrict__ b_b,
    const float* __restrict__ W_d, const float* __restrict__ b_d,
    float* __restrict__ out)
{
  const int b    = blockIdx.x;
  const int tid  = threadIdx.x;
  const int lane = tid & 63;      // unit u = lane
  const int g    = tid >> 6;      // wave == gate: 0:i 1:f 2:g(tanh) 3:o

  __shared__ int   tok_s [TT + 8];
  __shared__ int   ctok_s[TT + 8];      // compacted active tokens
  __shared__ float emb_s[6 * 64];
  __shared__ float zx_s [6 * 272];      // fwd table, [v][g*68 + u] (padded)
  __shared__ float zxb_s[6 * 256];      // bwd table (epilogue only)
  __shared__ float act_s[2][4 * 68];    // [buf][g*68 + u]
  __shared__ int   wsum[4];

  // ---- stage tokens (int4) + emb ----
  {
    const int4* tsrc = (const int4*)(tokens + b * TT);
    int4* tdst = (int4*)tok_s;
    for (int i = tid; i < TT / 4; i += 256) tdst[i] = tsrc[i];
    if (tid < 8) { tok_s[TT + tid] = 0; ctok_s[TT + tid] = 0; }
    for (int i = tid; i < 384; i += 256) emb_s[i] = emb[i];
  }
  __syncthreads();

  // ---- compact active tokens: stable parallel scan (8 tokens/thread) ----
  int mytok[8];
  int cnt = 0;
#pragma unroll
  for (int j = 0; j < 8; ++j) {
    mytok[j] = tok_s[tid * 8 + j];
    cnt += (mytok[j] != 0);
  }
  int inc = cnt;                        // wave-inclusive scan
#pragma unroll
  for (int off = 1; off < 64; off <<= 1) {
    int v = __shfl_up(inc, off, 64);
    if (lane >= off) inc += v;
  }
  if (lane == 63) wsum[g] = inc;
  __syncthreads();
  int base = 0;
#pragma unroll
  for (int w = 0; w < 4; ++w) base += (w < g) ? wsum[w] : 0;
  int pos = base + inc - cnt;           // exclusive global offset
#pragma unroll
  for (int j = 0; j < 8; ++j)
    if (mytok[j] != 0) ctok_s[pos++] = mytok[j];
  const int nact = __builtin_amdgcn_readfirstlane(wsum[0] + wsum[1] + wsum[2] + wsum[3]);

  // ---- zx tables (thread owns column (g,lane), both dirs) ----
  {
    float af[6], ab[6];
#pragma unroll
    for (int v = 0; v < 6; ++v) { af[v] = b_f[tid]; ab[v] = b_b[tid]; }
    for (int e = 0; e < 64; ++e) {
      const float wf = W_f[e * 256 + tid];
      const float wb = W_b[e * 256 + tid];
#pragma unroll
      for (int v = 0; v < 6; ++v) {
        af[v] = fmaf(emb_s[v * 64 + e], wf, af[v]);
        ab[v] = fmaf(emb_s[v * 64 + e], wb, ab[v]);
      }
    }
#pragma unroll
    for (int v = 0; v < 6; ++v) {
      zx_s [v * 272 + g * 68 + lane] = af[v];
      zxb_s[v * 256 + tid] = ab[v];
    }
  }

  // ---- U column for (gate g, unit lane): 64 AGPRs ----
  const int cb = (g << 6) + lane;
  UFOR_ALL(DECLUA)

  __syncthreads();

  // wave-uniform activation constants: y = ya*rcp(1+exp2(z*m1)) + yb
  const float m1 = (g == 2) ? (-2.f * L2E) : (-L2E);
  const float ya = (g == 2) ? 2.f : 1.f;
  const float yb = (g == 2) ? -1.f : 0.f;
  const int   goff = g * 68 + lane;

  // h,c replicated per-lane in EVERY wave: lane l holds h[l], c[l]
  float h_reg = 0.f, c_reg = 0.f;
  int   buf = 0;
  int   tokc = ctok_s[0];

  for (int s = 0; s < nact; ++s) {
    const int tokn = ctok_s[s + 1];              // prefetch (pad-safe)
    const float zxv = zx_s[tokc * 272 + goff];   // issues under FMA block
    float a0 = 0.f, a1 = 0.f, a2 = 0.f, a3 = 0.f;
    FMA4(0, 1, 2, 3)     FMA4(4, 5, 6, 7)     FMA4(8, 9, 10, 11)   FMA4(12, 13, 14, 15)
    FMA4(16, 17, 18, 19) FMA4(20, 21, 22, 23) FMA4(24, 25, 26, 27) FMA4(28, 29, 30, 31)
    FMA4(32, 33, 34, 35) FMA4(36, 37, 38, 39) FMA4(40, 41, 42, 43) FMA4(44, 45, 46, 47)
    FMA4(48, 49, 50, 51) FMA4(52, 53, 54, 55) FMA4(56, 57, 58, 59) FMA4(60, 61, 62, 63)
    const float z = zxv + ((a0 + a1) + (a2 + a3));
    const float y = fmaf(ya, frcp(1.f + fexp2(z * m1)), yb);
    act_s[buf][goff] = y;
    __syncthreads();
    const float ai  = act_s[buf][lane];
    const float af2 = act_s[buf][68 + lane];
    const float ag  = act_s[buf][136 + lane];
    const float ao  = act_s[buf][204 + lane];
    c_reg = fmaf(af2, c_reg, ai * ag);           // replicated update, all waves
    h_reg = ao * ftanh(c_reg);
    buf ^= 1;                                    // WAR-safe: 2 barriers apart
    tokc = tokn;
  }

  // ---- epilogue: bwd single step from zero state + dense + reduce ----
  if (tid < 64) {                                // wave 0 holds h[lane] = h_reg
    const float hf   = h_reg;
    const int   tokL = tok_s[TT - 1];
    float hbv = 0.f;
    if (tokL != 0) {
      const float zi = zxb_s[tokL * 256 + tid];
      const float zg = zxb_s[tokL * 256 + 128 + tid];
      const float zo = zxb_s[tokL * 256 + 192 + tid];
      const float cn = fsigm(zi) * ftanh(zg);    // c0=0 -> forget term vanishes
      hbv = fsigm(zo) * ftanh(cn);
    }
    float pr = fmaf(hf, W_d[tid], hbv * W_d[64 + tid]);
#pragma unroll
    for (int off = 32; off > 0; off >>= 1) pr += __shfl_xor(pr, off, 64);
    if (tid == 0) out[b] = pr + b_d[0];
  }
}

extern "C" void kernel_launch(void* const* d_in, const int* in_sizes, int n_in,
                              void* d_out, int out_size, void* d_ws, size_t ws_size,
                              hipStream_t stream) {
  const int*   tokens = (const int*)d_in[0];
  const float* emb    = (const float*)d_in[1];
  const float* W_f    = (const float*)d_in[2];
  const float* U_f    = (const float*)d_in[3];
  const float* b_f    = (const float*)d_in[4];
  const float* W_b    = (const float*)d_in[5];
  const float* U_b    = (const float*)d_in[6];
  (void)U_b;  // bwd is a single step from zero state: h@U_b == 0
  const float* b_b    = (const float*)d_in[7];
  const float* W_d    = (const float*)d_in[8];
  const float* b_d    = (const float*)d_in[9];
  float* out = (float*)d_out;
  (void)d_ws; (void)ws_size;

  lstm_fused<<<256, 256, 0, stream>>>(tokens, emb, W_f, U_f, b_f, W_b, b_b,
                                      W_d, b_d, out);
}

// Round 12
// 739.485 us; speedup vs baseline: 1.3323x; 1.1910x over previous
//
#include <hip/hip_runtime.h>

// Bidirectional masked LSTM, only last timestep consumed.
//   B=256, T=2048, VOCAB=6, EMB=64, HID=64.  One block per batch element/CU.
// Algebraic reductions (validated rounds 0-10, absmax 0.0):
//   - bwd direction at t=T-1 == ONE lstm step from zero state (U_b unused).
//   - x@W+b has only 6 values per direction -> zx tables.
//   - tok==0 steps are no-ops -> token stream compacted once.
// Ledger: R6 (U spill-managed by compiler) = 706us BEST; R9 AGPR+volatile =
//   967 (asm fences serialize); R10 AGPR non-volatile = 862 (+270 VALU
//   cyc/step of read instructions). FETCH_SIZE==1855MB in ALL variants incl.
//   the memory-op-free loop -> ambient artifact, ignore it as a signal.
// Round-11/12 single change vs R6: the readlane->fmac pairs were ADJACENT
//   (VALU writes SGPR, next VALU reads it -> HW wait states x64/step).
//   Split into software-pipelined groups of 16: RL16(g+1) issues before
//   FMA16(g), so every SGPR is written >=16 instrs before use.
// Predicted: dur 706 -> ~530-620us, VALUBusy 51 -> 60-68%.
// (R12 = identical resubmit; R11 bench lost to GPU acquisition timeout.)

#define TT 2048
#define L2E 1.4426950408889634f

__device__ __forceinline__ float fexp2(float x) { return __builtin_amdgcn_exp2f(x); }
__device__ __forceinline__ float frcp(float x)  { return __builtin_amdgcn_rcpf(x); }
__device__ __forceinline__ float fsigm(float x) { return frcp(1.f + fexp2(-L2E * x)); }
__device__ __forceinline__ float ftanh(float x) { return fmaf(2.f, frcp(1.f + fexp2(-2.f * L2E * x)), -1.f); }
__device__ __forceinline__ float readlane_f(float v, int l) {
  return __builtin_bit_cast(float, __builtin_amdgcn_readlane(__builtin_bit_cast(int, v), l));
}

// apply X to 0..63
#define UFOR_ALL(X) \
  X(0)  X(1)  X(2)  X(3)  X(4)  X(5)  X(6)  X(7)  \
  X(8)  X(9)  X(10) X(11) X(12) X(13) X(14) X(15) \
  X(16) X(17) X(18) X(19) X(20) X(21) X(22) X(23) \
  X(24) X(25) X(26) X(27) X(28) X(29) X(30) X(31) \
  X(32) X(33) X(34) X(35) X(36) X(37) X(38) X(39) \
  X(40) X(41) X(42) X(43) X(44) X(45) X(46) X(47) \
  X(48) X(49) X(50) X(51) X(52) X(53) X(54) X(55) \
  X(56) X(57) X(58) X(59) X(60) X(61) X(62) X(63)

#define DECLU(k) float U##k = Uv[(k) * 256 + cb];
#define PINU(k)  asm volatile("" : "+v"(U##k));

// broadcast group of 16: h[base..base+16) -> SGPR-resident uniforms
#define RL16(B, base)                                                     \
  B[0]  = readlane_f(h_reg, (base) + 0);  B[1]  = readlane_f(h_reg, (base) + 1);  \
  B[2]  = readlane_f(h_reg, (base) + 2);  B[3]  = readlane_f(h_reg, (base) + 3);  \
  B[4]  = readlane_f(h_reg, (base) + 4);  B[5]  = readlane_f(h_reg, (base) + 5);  \
  B[6]  = readlane_f(h_reg, (base) + 6);  B[7]  = readlane_f(h_reg, (base) + 7);  \
  B[8]  = readlane_f(h_reg, (base) + 8);  B[9]  = readlane_f(h_reg, (base) + 9);  \
  B[10] = readlane_f(h_reg, (base) + 10); B[11] = readlane_f(h_reg, (base) + 11); \
  B[12] = readlane_f(h_reg, (base) + 12); B[13] = readlane_f(h_reg, (base) + 13); \
  B[14] = readlane_f(h_reg, (base) + 14); B[15] = readlane_f(h_reg, (base) + 15);

// FMA group of 16 consuming buffer B against named U regs u0..u15
#define FMA16(B, u0,u1,u2,u3,u4,u5,u6,u7,u8,u9,u10,u11,u12,u13,u14,u15)   \
  a0 = fmaf(B[0],  u0,  a0); a1 = fmaf(B[1],  u1,  a1);                   \
  a2 = fmaf(B[2],  u2,  a2); a3 = fmaf(B[3],  u3,  a3);                   \
  a0 = fmaf(B[4],  u4,  a0); a1 = fmaf(B[5],  u5,  a1);                   \
  a2 = fmaf(B[6],  u6,  a2); a3 = fmaf(B[7],  u7,  a3);                   \
  a0 = fmaf(B[8],  u8,  a0); a1 = fmaf(B[9],  u9,  a1);                   \
  a2 = fmaf(B[10], u10, a2); a3 = fmaf(B[11], u11, a3);                   \
  a0 = fmaf(B[12], u12, a0); a1 = fmaf(B[13], u13, a1);                   \
  a2 = fmaf(B[14], u14, a2); a3 = fmaf(B[15], u15, a3);

__global__ __launch_bounds__(256, 1) void lstm_fused(
    const int* __restrict__ tokens,
    const float* __restrict__ emb,
    const float* __restrict__ W_f, const float* __restrict__ U_f, const float* __restrict__ b_f,
    const float* __restrict__ W_b, const float* __restrict__ b_b,
    const float* __restrict__ W_d, const float* __restrict__ b_d,
    float* __restrict__ out)
{
  const int b    = blockIdx.x;
  const int tid  = threadIdx.x;
  const int lane = tid & 63;      // unit u = lane
  const int g    = tid >> 6;      // wave == gate: 0:i 1:f 2:g(tanh) 3:o

  __shared__ int   tok_s [TT + 8];
  __shared__ int   ctok_s[TT + 8];      // compacted active tokens
  __shared__ float emb_s[6 * 64];
  __shared__ float zx_s [6 * 272];      // fwd table, [v][g*68 + u] (padded)
  __shared__ float zxb_s[6 * 256];      // bwd table (epilogue only)
  __shared__ float act_s[2][4 * 68];    // [buf][g*68 + u]
  __shared__ int   wsum[4];

  // ---- stage tokens (int4) + emb ----
  {
    const int4* tsrc = (const int4*)(tokens + b * TT);
    int4* tdst = (int4*)tok_s;
    for (int i = tid; i < TT / 4; i += 256) tdst[i] = tsrc[i];
    if (tid < 8) { tok_s[TT + tid] = 0; ctok_s[TT + tid] = 0; }
    for (int i = tid; i < 384; i += 256) emb_s[i] = emb[i];
  }
  __syncthreads();

  // ---- compact active tokens: stable parallel scan (8 tokens/thread) ----
  int mytok[8];
  int cnt = 0;
#pragma unroll
  for (int j = 0; j < 8; ++j) {
    mytok[j] = tok_s[tid * 8 + j];
    cnt += (mytok[j] != 0);
  }
  int inc = cnt;                        // wave-inclusive scan
#pragma unroll
  for (int off = 1; off < 64; off <<= 1) {
    int v = __shfl_up(inc, off, 64);
    if (lane >= off) inc += v;
  }
  if (lane == 63) wsum[g] = inc;
  __syncthreads();
  int base = 0;
#pragma unroll
  for (int w = 0; w < 4; ++w) base += (w < g) ? wsum[w] : 0;
  int pos = base + inc - cnt;           // exclusive global offset
#pragma unroll
  for (int j = 0; j < 8; ++j)
    if (mytok[j] != 0) ctok_s[pos++] = mytok[j];
  const int nact = __builtin_amdgcn_readfirstlane(wsum[0] + wsum[1] + wsum[2] + wsum[3]);

  // ---- zx tables (thread owns column (g,lane), both dirs) ----
  {
    float af[6], ab[6];
#pragma unroll
    for (int v = 0; v < 6; ++v) { af[v] = b_f[tid]; ab[v] = b_b[tid]; }
    for (int e = 0; e < 64; ++e) {
      const float wf = W_f[e * 256 + tid];
      const float wb = W_b[e * 256 + tid];
#pragma unroll
      for (int v = 0; v < 6; ++v) {
        af[v] = fmaf(emb_s[v * 64 + e], wf, af[v]);
        ab[v] = fmaf(emb_s[v * 64 + e], wb, ab[v]);
      }
    }
#pragma unroll
    for (int v = 0; v < 6; ++v) {
      zx_s [v * 272 + g * 68 + lane] = af[v];
      zxb_s[v * 256 + tid] = ab[v];
    }
  }

  // ---- U column for (gate g, unit lane): named scalars, volatile loads
  //      (R6 configuration — measured best) ----
  const volatile float* Uv = U_f;
  const int cb = (g << 6) + lane;
  UFOR_ALL(DECLU)

  __syncthreads();

  // wave-uniform activation constants: y = ya*rcp(1+exp2(z*m1)) + yb
  const float m1 = (g == 2) ? (-2.f * L2E) : (-L2E);
  const float ya = (g == 2) ? 2.f : 1.f;
  const float yb = (g == 2) ? -1.f : 0.f;
  const int   goff = g * 68 + lane;

  // h,c replicated per-lane in EVERY wave: lane l holds h[l], c[l]
  float h_reg = 0.f, c_reg = 0.f;
  int   buf = 0;
  int   tokc = ctok_s[0];

  for (int s = 0; s < nact; ++s) {
    UFOR_ALL(PINU)                               // keep U live (R6 config)

    const int tokn = ctok_s[s + 1];              // prefetch (pad-safe)
    const float zxv = zx_s[tokc * 272 + goff];   // issues under FMA block
    float a0 = 0.f, a1 = 0.f, a2 = 0.f, a3 = 0.f;
    float hsA[16], hsB[16];
    // software-pipelined broadcast: RL group g+1 issues before FMA group g,
    // so each SGPR is written >=16 instructions before its first read.
    RL16(hsA, 0)
    RL16(hsB, 16)
    FMA16(hsA, U0,U1,U2,U3,U4,U5,U6,U7,U8,U9,U10,U11,U12,U13,U14,U15)
    RL16(hsA, 32)
    FMA16(hsB, U16,U17,U18,U19,U20,U21,U22,U23,U24,U25,U26,U27,U28,U29,U30,U31)
    RL16(hsB, 48)
    FMA16(hsA, U32,U33,U34,U35,U36,U37,U38,U39,U40,U41,U42,U43,U44,U45,U46,U47)
    FMA16(hsB, U48,U49,U50,U51,U52,U53,U54,U55,U56,U57,U58,U59,U60,U61,U62,U63)

    const float z = zxv + ((a0 + a1) + (a2 + a3));
    const float y = fmaf(ya, frcp(1.f + fexp2(z * m1)), yb);
    act_s[buf][goff] = y;
    __syncthreads();
    const float ai  = act_s[buf][lane];
    const float af2 = act_s[buf][68 + lane];
    const float ag  = act_s[buf][136 + lane];
    const float ao  = act_s[buf][204 + lane];
    c_reg = fmaf(af2, c_reg, ai * ag);           // replicated update, all waves
    h_reg = ao * ftanh(c_reg);
    buf ^= 1;                                    // WAR-safe: 2 barriers apart
    tokc = tokn;
  }

  // ---- epilogue: bwd single step from zero state + dense + reduce ----
  if (tid < 64) {                                // wave 0 holds h[lane] = h_reg
    const float hf   = h_reg;
    const int   tokL = tok_s[TT - 1];
    float hbv = 0.f;
    if (tokL != 0) {
      const float zi = zxb_s[tokL * 256 + tid];
      const float zg = zxb_s[tokL * 256 + 128 + tid];
      const float zo = zxb_s[tokL * 256 + 192 + tid];
      const float cn = fsigm(zi) * ftanh(zg);    // c0=0 -> forget term vanishes
      hbv = fsigm(zo) * ftanh(cn);
    }
    float pr = fmaf(hf, W_d[tid], hbv * W_d[64 + tid]);
#pragma unroll
    for (int off = 32; off > 0; off >>= 1) pr += __shfl_xor(pr, off, 64);
    if (tid == 0) out[b] = pr + b_d[0];
  }
}

extern "C" void kernel_launch(void* const* d_in, const int* in_sizes, int n_in,
                              void* d_out, int out_size, void* d_ws, size_t ws_size,
                              hipStream_t stream) {
  const int*   tokens = (const int*)d_in[0];
  const float* emb    = (const float*)d_in[1];
  const float* W_f    = (const float*)d_in[2];
  const float* U_f    = (const float*)d_in[3];
  const float* b_f    = (const float*)d_in[4];
  const float* W_b    = (const float*)d_in[5];
  const float* U_b    = (const float*)d_in[6];
  (void)U_b;  // bwd is a single step from zero state: h@U_b == 0
  const float* b_b    = (const float*)d_in[7];
  const float* W_d    = (const float*)d_in[8];
  const float* b_d    = (const float*)d_in[9];
  float* out = (float*)d_out;
  (void)d_ws; (void)ws_size;

  lstm_fused<<<256, 256, 0, stream>>>(tokens, emb, W_f, U_f, b_f, W_b, b_b,
                                      W_d, b_d, out);
}